// Round 7
// baseline (2377.787 us; speedup 1.0000x reference)
//
#include <hip/hip_runtime.h>
#include <hip/hip_bf16.h>

typedef __hip_bfloat16 bf16;
typedef unsigned short u16;
typedef unsigned long long u64;
using frag  = __attribute__((ext_vector_type(8))) short;   // 8 bf16
using f32x4 = __attribute__((ext_vector_type(4))) float;   // 4 fp32 acc

static constexpr int T_  = 128;
static constexpr int B_  = 512;
static constexpr int H_  = 512;
static constexpr int K_  = 512;
static constexpr int G4_ = 2048;
static constexpr int NWG = 256;

// dynamic LDS: weights 128KB (frag-blocked) + partials 16KB + hstage 10KB
static constexpr size_t W_BYTES = 131072;                 // 128 blocks x 1KB
static constexpr size_t P_BYTES = 16384;                  // 2 slots x 8 frags x 64 lanes x 16B
static constexpr size_t HS_BYTES = 4 * 32 * 20 * 4;       // 10240
static constexpr size_t SMEM_BYTES = W_BYTES + P_BYTES + HS_BYTES;

// coherent (agent-scope, L1/L2-bypassing) 16B load as 2x b64 relaxed atomics
__device__ __forceinline__ frag ld_coh(const u16* p) {
  u64 lo = __hip_atomic_load((const u64*)p,       __ATOMIC_RELAXED, __HIP_MEMORY_SCOPE_AGENT);
  u64 hi = __hip_atomic_load((const u64*)(p + 4), __ATOMIC_RELAXED, __HIP_MEMORY_SCOPE_AGENT);
  union { u64 q[2]; frag f; } u;
  u.q[0] = lo; u.q[1] = hi;
  return u.f;
}

// ---------------- setup kernels ----------------

__global__ void k_f32_to_bf16_v4(const float4* __restrict__ src,
                                 ushort4* __restrict__ dst, int n4) {
  int i = blockIdx.x * blockDim.x + threadIdx.x;
  int stride = gridDim.x * blockDim.x;
  for (; i < n4; i += stride) {
    float4 v = src[i];
    ushort4 o;
    bf16 t0 = __float2bfloat16(v.x); o.x = *reinterpret_cast<u16*>(&t0);
    bf16 t1 = __float2bfloat16(v.y); o.y = *reinterpret_cast<u16*>(&t1);
    bf16 t2 = __float2bfloat16(v.z); o.z = *reinterpret_cast<u16*>(&t2);
    bf16 t3 = __float2bfloat16(v.w); o.w = *reinterpret_cast<u16*>(&t3);
    dst[i] = o;
  }
}

__global__ void k_bias(const float* __restrict__ bih0, const float* __restrict__ bhh0,
                       const float* __restrict__ bih1, const float* __restrict__ bhh1,
                       float* __restrict__ bsum0, float* __restrict__ bsum1) {
  int i = blockIdx.x * blockDim.x + threadIdx.x;
  if (i < G4_) {
    bsum0[i] = bih0[i] + bhh0[i];
    bsum1[i] = bih1[i] + bhh1[i];
  }
}

// initial h: layer0 -> h0buf parity 0, layer1 -> h1buf parity 1
__global__ void k_init2(const float* __restrict__ h0,
                        u16* __restrict__ h0buf, u16* __restrict__ h1buf) {
  int i = blockIdx.x * blockDim.x + threadIdx.x;
  int n = B_ * H_;
  if (i < n) {
    bf16 a = __float2bfloat16(h0[i]);
    bf16 b = __float2bfloat16(h0[n + i]);
    h0buf[i] = *reinterpret_cast<u16*>(&a);          // parity 0
    h1buf[n + i] = *reinterpret_cast<u16*>(&b);      // parity 1
  }
}

__global__ void k_zero(int* p) {
  int i = blockIdx.x * blockDim.x + threadIdx.x;
  if (i < 128) p[i] = 0;
}

// ---------------- persistent LSTM kernel ----------------
// 256 WGs x 512 thr (8 waves). XCD-locality: lb = wg&7 -> layer = lb>>2, bg = lb&3;
// cg = wg>>3. WG owns batch rows [bg*128,+128) x h-cols [cg*16,+16) for its layer.
// Waves: wave = rg*2 + khalf; rg in 0..3 owns rows [rg*32,+32); khalf 0 = x-part
// (K 0..511 @ W_ih), khalf 1 = h-part (K 0..511 @ W_hh, reset-masked).
// Weights in LDS, FRAG-BLOCKED: block fb = ni*32 + (khalf*16 + kslot); within a
// block lane l holds W[gate ni, col hbase+(l&15)][kslot*32 + (l>>4)*8 + 0..7]
// (16B). ds_read_b128 at (fb*64+lane)*16B is lane-consecutive -> conflict-free.
// Per phase: all 32 A-frags hoisted to regs (one L3 round-trip), MFMA stream,
// cross-K-half fp32 reduction via 16KB LDS (2 rounds), elementwise in khalf0
// waves (c-state in regs), packed coherent h stores, pair-domain barrier
// (relaxed atomics, no cache-maintenance fences).
__global__ __launch_bounds__(512, 2)
void k_main(const u16* __restrict__ latb,
            const u16* __restrict__ W0i, const u16* __restrict__ W0h,
            const u16* __restrict__ W1i, const u16* __restrict__ W1h,
            const float* __restrict__ bs0, const float* __restrict__ bs1,
            const int* __restrict__ reset,   // (T,B)
            const float* __restrict__ c0,    // (2,B,H)
            u16* __restrict__ h0buf,         // [2][B][H]
            u16* __restrict__ h1buf,         // [2][B][H]
            float* __restrict__ hidden,      // (T,B,H)
            float* __restrict__ hn,          // (2,B,H)
            float* __restrict__ cn,          // (2,B,H)
            int* __restrict__ ctr) {         // 128 ints: [bg*32]=L0, [bg*32+16]=L1
  extern __shared__ char smem_raw[];
  u16*   wlds     = (u16*)smem_raw;                        // 128KB frag blocks
  float* partials = (float*)(smem_raw + W_BYTES);          // [2][8][64][4] f32
  float* hstage   = (float*)(smem_raw + W_BYTES + P_BYTES);// [4][32][20] f32
  __shared__ int rstlds[128];

  const int tid   = threadIdx.x;
  const int wg    = blockIdx.x;
  const int lb    = wg & 7;
  const int layer = lb >> 2;
  const int bg    = lb & 3;
  const int cg    = wg >> 3;
  const int hbase = cg * 16;
  const int rowbase = bg * 128;
  const int wave  = tid >> 6;                  // 0..7
  const int lane  = tid & 63;
  const int r16   = lane & 15;
  const int kq    = lane >> 4;                 // 0..3
  const int rg    = wave >> 1;                 // row-group 0..3
  const int khalf = wave & 1;                  // 0 = x-part, 1 = h-part
  const int wrow_local = rg * 32;
  const int wrow0 = rowbase + wrow_local;

  const u16* Wih = layer ? W1i : W0i;
  const u16* Whh = layer ? W1h : W0h;
  const float* bs = layer ? bs1 : bs0;
  u16* hself = layer ? h1buf : h0buf;
  int* ctrSelf  = ctr + bg * 32 + (layer ? 16 : 0);
  int* ctrOther = ctr + bg * 32 + (layer ? 0 : 16);

  // ---- stage weights into frag-blocked LDS (once) ----
  // chunk c = fb*64 + l ; fb = ni*32 + kslot ; kslot<16 -> W_ih, else W_hh
  for (int it = 0; it < 16; ++it) {
    int c = it * 512 + tid;                    // 0..8191
    int fb = c >> 6, l = c & 63;
    int ni = fb >> 5, kslot = fb & 31;
    int col = hbase + (l & 15);
    int klocal = (kslot & 15) * 32 + (l >> 4) * 8;
    const u16* M = (kslot < 16) ? Wih : Whh;
    const u16* src = M + (size_t)(ni * H_ + col) * K_ + klocal;
    *(float4*)(wlds + ((size_t)c) * 8) = *(const float4*)src;
  }

  // per-lane gate biases (col = hbase + r16)
  float bias[4];
  #pragma unroll
  for (int g = 0; g < 4; ++g) bias[g] = bs[g * H_ + hbase + r16];

  // c-state registers (meaningful in khalf0 waves): row = wrow0+mi*16+kq*4+j
  float creg[2][4];
  #pragma unroll
  for (int mi = 0; mi < 2; ++mi)
    #pragma unroll
    for (int j = 0; j < 4; ++j)
      creg[mi][j] = c0[((size_t)layer * B_ + (wrow0 + mi * 16 + kq * 4 + j)) * H_
                       + hbase + r16];

  __syncthreads();

  for (int p = 0; p <= T_; ++p) {
    const int t = layer ? (p - 1) : p;
    const bool active = (t >= 0 && t < T_);
    float hnew_r[2][4], cnew_r[2][4];

    if (active) {
      if (tid < 128) rstlds[tid] = reset[(size_t)t * B_ + rowbase + tid];
      __syncthreads();

      u16* Hn = hself + (size_t)((p + 1) & 1) * B_ * H_;

      // A source for this wave's K-half
      const u16* Asrc;
      bool coh;
      if (layer == 0) {
        Asrc = khalf ? (hself + (size_t)(p & 1) * B_ * H_)
                     : (latb + (size_t)t * B_ * K_);
        coh = (khalf != 0);
      } else {
        Asrc = khalf ? (hself + (size_t)(p & 1) * B_ * H_)
                     : (h0buf + (size_t)(p & 1) * B_ * H_);
        coh = true;
      }

      // ---- hoist all A-frags to registers (one L3 round-trip) ----
      frag a[2][16];
      const frag zf = {};
      #pragma unroll
      for (int m = 0; m < 2; ++m) {
        const u16* base = Asrc + (size_t)(wrow0 + m * 16 + r16) * 512 + kq * 8;
        const int ra = khalf ? rstlds[wrow_local + m * 16 + r16] : 0;
        if (coh) {
          #pragma unroll
          for (int s = 0; s < 16; ++s)
            a[m][s] = ra ? zf : ld_coh(base + s * 32);
        } else {
          #pragma unroll
          for (int s = 0; s < 16; ++s)
            a[m][s] = *reinterpret_cast<const frag*>(base + s * 32);
        }
      }

      // ---- MFMA stream: conflict-free frag-blocked B reads ----
      f32x4 acc[2][4] = {};
      #pragma unroll
      for (int s = 0; s < 16; ++s) {
        #pragma unroll
        for (int ni = 0; ni < 4; ++ni) {
          frag b = *reinterpret_cast<const frag*>(
              wlds + ((size_t)((ni * 32 + khalf * 16 + s) * 64 + lane)) * 8);
          acc[0][ni] = __builtin_amdgcn_mfma_f32_16x16x32_bf16(a[0][s], b, acc[0][ni], 0, 0, 0);
          acc[1][ni] = __builtin_amdgcn_mfma_f32_16x16x32_bf16(a[1][s], b, acc[1][ni], 0, 0, 0);
        }
      }

      // ---- cross-K-half reduction via LDS (2 rounds, lane-major frags) ----
      // round 1: row-groups 0,1 ; round 2: row-groups 2,3
      if (wave == 1 || wave == 3) {
        #pragma unroll
        for (int mi = 0; mi < 2; ++mi)
          #pragma unroll
          for (int ni = 0; ni < 4; ++ni)
            *(f32x4*)(partials + ((size_t)((rg * 8 + mi * 4 + ni) * 64 + lane)) * 4)
                = acc[mi][ni];
      }
      __syncthreads();
      if (wave == 0 || wave == 2) {
        #pragma unroll
        for (int mi = 0; mi < 2; ++mi)
          #pragma unroll
          for (int ni = 0; ni < 4; ++ni)
            acc[mi][ni] += *(const f32x4*)(partials
                + ((size_t)((rg * 8 + mi * 4 + ni) * 64 + lane)) * 4);
      }
      __syncthreads();
      if (wave == 5 || wave == 7) {
        #pragma unroll
        for (int mi = 0; mi < 2; ++mi)
          #pragma unroll
          for (int ni = 0; ni < 4; ++ni)
            *(f32x4*)(partials + ((size_t)(((rg - 2) * 8 + mi * 4 + ni) * 64 + lane)) * 4)
                = acc[mi][ni];
      }
      __syncthreads();
      if (wave == 4 || wave == 6) {
        #pragma unroll
        for (int mi = 0; mi < 2; ++mi)
          #pragma unroll
          for (int ni = 0; ni < 4; ++ni)
            acc[mi][ni] += *(const f32x4*)(partials
                + ((size_t)(((rg - 2) * 8 + mi * 4 + ni) * 64 + lane)) * 4);
      }

      // ---- elementwise + packed coherent h stores (khalf0 waves only) ----
      if (khalf == 0) {
        float* hs = hstage + (size_t)rg * 32 * 20;
        #pragma unroll
        for (int mi = 0; mi < 2; ++mi) {
          #pragma unroll
          for (int j = 0; j < 4; ++j) {
            const int lrow = wrow_local + mi * 16 + kq * 4 + j;
            float gi = acc[mi][0][j] + bias[0];
            float gf = acc[mi][1][j] + bias[1];
            float gg = acc[mi][2][j] + bias[2];
            float go = acc[mi][3][j] + bias[3];
            float iv = 1.f / (1.f + __expf(-gi));
            float fv = 1.f / (1.f + __expf(-gf));
            float gv = 1.f - 2.f / (__expf(2.f * gg) + 1.f);   // tanh
            float ov = 1.f / (1.f + __expf(-go));
            float ce = rstlds[lrow] ? 0.f : creg[mi][j];
            float cnew = fv * ce + iv * gv;
            float hnew = ov * (1.f - 2.f / (__expf(2.f * cnew) + 1.f));
            creg[mi][j] = cnew;
            cnew_r[mi][j] = cnew;
            hnew_r[mi][j] = hnew;
            hs[(mi * 16 + kq * 4 + j) * 20 + r16] = hnew;   // wave-local
          }
        }
        // pack: lane -> row = lane>>1, cols (lane&1)*8 .. +7 ; 2x u64 stores
        {
          const int prow = lane >> 1;
          const int pc8  = (lane & 1) * 8;
          float4 v0 = *(const float4*)(hs + prow * 20 + pc8);
          float4 v1 = *(const float4*)(hs + prow * 20 + pc8 + 4);
          bf16 b0 = __float2bfloat16(v0.x), b1 = __float2bfloat16(v0.y);
          bf16 b2 = __float2bfloat16(v0.z), b3 = __float2bfloat16(v0.w);
          bf16 b4 = __float2bfloat16(v1.x), b5 = __float2bfloat16(v1.y);
          bf16 b6 = __float2bfloat16(v1.z), b7 = __float2bfloat16(v1.w);
          u64 pk0 = (u64)*reinterpret_cast<u16*>(&b0)
                  | ((u64)*reinterpret_cast<u16*>(&b1) << 16)
                  | ((u64)*reinterpret_cast<u16*>(&b2) << 32)
                  | ((u64)*reinterpret_cast<u16*>(&b3) << 48);
          u64 pk1 = (u64)*reinterpret_cast<u16*>(&b4)
                  | ((u64)*reinterpret_cast<u16*>(&b5) << 16)
                  | ((u64)*reinterpret_cast<u16*>(&b6) << 32)
                  | ((u64)*reinterpret_cast<u16*>(&b7) << 48);
          u16* dst = Hn + (size_t)(wrow0 + prow) * H_ + hbase + pc8;
          __hip_atomic_store((u64*)dst,     pk0, __ATOMIC_RELAXED, __HIP_MEMORY_SCOPE_AGENT);
          __hip_atomic_store((u64*)(dst+4), pk1, __ATOMIC_RELAXED, __HIP_MEMORY_SCOPE_AGENT);
        }
      }
    }

    // barrier arrival (drain coherent h stores first)
    if (p < T_) {
      asm volatile("s_waitcnt vmcnt(0)" ::: "memory");
      __syncthreads();
      if (tid == 0)
        __hip_atomic_fetch_add(ctrSelf, 1, __ATOMIC_RELAXED, __HIP_MEMORY_SCOPE_AGENT);
    }

    // deferred output stores (overlap with barrier poll)
    if (active && khalf == 0) {
      float* hidden_t = hidden + (size_t)t * B_ * H_;
      #pragma unroll
      for (int mi = 0; mi < 2; ++mi)
        #pragma unroll
        for (int j = 0; j < 4; ++j) {
          const size_t off = (size_t)(wrow0 + mi * 16 + kq * 4 + j) * H_ + hbase + r16;
          if (layer) hidden_t[off] = hnew_r[mi][j];
          if (t == T_ - 1) {
            hn[(size_t)layer * B_ * H_ + off] = hnew_r[mi][j];
            cn[(size_t)layer * B_ * H_ + off] = cnew_r[mi][j];
          }
        }
    }

    // barrier wait: both layer counters of this pair-domain at phase p+1
    if (p < T_) {
      if (tid == 0) {
        const int target = 32 * (p + 1);
        while (true) {
          int a = __hip_atomic_load(ctrSelf,  __ATOMIC_RELAXED, __HIP_MEMORY_SCOPE_AGENT);
          int b = __hip_atomic_load(ctrOther, __ATOMIC_RELAXED, __HIP_MEMORY_SCOPE_AGENT);
          if (a >= target && b >= target) break;
          __builtin_amdgcn_s_sleep(2);
        }
      }
      __syncthreads();
    }
  }
}

// ---------------- host ----------------

extern "C" void kernel_launch(void* const* d_in, const int* in_sizes, int n_in,
                              void* d_out, int out_size, void* d_ws, size_t ws_size,
                              hipStream_t stream) {
  (void)in_sizes; (void)n_in; (void)out_size; (void)ws_size;

  const float* latent = (const float*)d_in[0];
  const float* h0in   = (const float*)d_in[1];
  const float* c0in   = (const float*)d_in[2];
  const int*   reset  = (const int*)d_in[3];
  const float* W_ih0  = (const float*)d_in[4];
  const float* W_hh0  = (const float*)d_in[5];
  const float* b_ih0  = (const float*)d_in[6];
  const float* b_hh0  = (const float*)d_in[7];
  const float* W_ih1  = (const float*)d_in[8];
  const float* W_hh1  = (const float*)d_in[9];
  const float* b_ih1  = (const float*)d_in[10];
  const float* b_hh1  = (const float*)d_in[11];

  float* out    = (float*)d_out;
  float* hidden = out;                               // (T,B,H)
  float* hn     = out + (size_t)T_ * B_ * H_;        // (2,B,H)
  float* cn     = hn + (size_t)2 * B_ * H_;          // (2,B,H)

  // workspace layout
  char* ws = (char*)d_ws;
  u16* latb  = (u16*)ws;                             // T*B*K bf16 (64 MiB)
  u16* wih0b = latb + (size_t)T_ * B_ * K_;
  u16* whh0b = wih0b + (size_t)G4_ * K_;
  u16* wih1b = whh0b + (size_t)G4_ * K_;
  u16* whh1b = wih1b + (size_t)G4_ * K_;
  float* bsum0 = (float*)(whh1b + (size_t)G4_ * K_);
  float* bsum1 = bsum0 + G4_;
  u16* h0buf = (u16*)(bsum1 + G4_);                  // [2][B][H]
  u16* h1buf = h0buf + (size_t)2 * B_ * H_;
  int* ctr   = (int*)(h1buf + (size_t)2 * B_ * H_);  // 128 ints

  // conversions / init (stream-ordered)
  int n_lat4 = T_ * B_ * K_ / 4;
  k_f32_to_bf16_v4<<<2048, 256, 0, stream>>>((const float4*)latent, (ushort4*)latb, n_lat4);
  int n_w4 = G4_ * K_ / 4;
  k_f32_to_bf16_v4<<<256, 256, 0, stream>>>((const float4*)W_ih0, (ushort4*)wih0b, n_w4);
  k_f32_to_bf16_v4<<<256, 256, 0, stream>>>((const float4*)W_hh0, (ushort4*)whh0b, n_w4);
  k_f32_to_bf16_v4<<<256, 256, 0, stream>>>((const float4*)W_ih1, (ushort4*)wih1b, n_w4);
  k_f32_to_bf16_v4<<<256, 256, 0, stream>>>((const float4*)W_hh1, (ushort4*)whh1b, n_w4);
  k_bias<<<(G4_ + 255) / 256, 256, 0, stream>>>(b_ih0, b_hh0, b_ih1, b_hh1, bsum0, bsum1);
  k_init2<<<(B_ * H_ + 255) / 256, 256, 0, stream>>>(h0in, h0buf, h1buf);
  k_zero<<<1, 128, 0, stream>>>(ctr);

  // persistent cooperative kernel
  hipFuncSetAttribute((const void*)k_main, hipFuncAttributeMaxDynamicSharedMemorySize,
                      (int)SMEM_BYTES);
  void* args[] = { (void*)&latb, (void*)&wih0b, (void*)&whh0b, (void*)&wih1b, (void*)&whh1b,
                   (void*)&bsum0, (void*)&bsum1, (void*)&reset, (void*)&c0in,
                   (void*)&h0buf, (void*)&h1buf, (void*)&hidden, (void*)&hn, (void*)&cn,
                   (void*)&ctr };
  hipLaunchCooperativeKernel((void*)k_main, dim3(NWG), dim3(512), args,
                             (unsigned int)SMEM_BYTES, stream);
}